// Round 13
// baseline (36.190 us; speedup 1.0000x reference)
//
#include <hip/hip_runtime.h>

// VQ-VAE vector quantizer, MI355X. 2 kernels.
//  K1 vq_prep : emb f32 -> Bg bf16 granule-planar [34][1024][8]; planes 32,33 =
//               bf16(-enorm/32) replicated (enorm baked into GEMM); zero ctrl.
//  K2 vq_main : 256 blocks x 512 thr, block = 64 rows x 1024 codes.
//    prologue: z -> As bf16 LDS (read-only after) + znorm -> znL
//    K loop:   BARRIER-FREE. B frags direct global->reg (L2-resident Bg),
//              ping-pong 2-chunk prefetch; A frags from LDS; 8 MFMA/chunk/wave.
//    epilogue: swapped-operand lane-local argmax -> idx; striped-cell loss;
//              gather emb rows -> out
// z: [16,256,32,32] f32, emb_w: [1024,256] f32
// out: z_q f32 (4194304) ++ loss scalar (1 float)

#define K_CODES 1024
#define D_DIM   256
#define ZQ_SIZE 4194304
#define NBLK    256

typedef unsigned short ushort_t;
typedef unsigned long long u64;
typedef short bf16x8 __attribute__((ext_vector_type(8)));
typedef float f32x16 __attribute__((ext_vector_type(16)));

struct Ctrl { u64 lsum[32]; unsigned done; unsigned pad[7]; };

__device__ __forceinline__ ushort_t f2bf(float x) {
    unsigned int b = __float_as_uint(x);
    b += 0x7fffu + ((b >> 16) & 1u);   // RNE
    return (ushort_t)(b >> 16);
}

// ---------------- K1: emb -> Bg (34 planes) ; zero ctrl ----------------
__global__ __launch_bounds__(512) void vq_prep(
        const float* __restrict__ emb, ushort_t* __restrict__ Bg, Ctrl* __restrict__ ctrl) {
    const int gi = blockIdx.x * 512 + threadIdx.x;   // [0, 32768)
    const int k = gi >> 5, g = gi & 31;
    const float4 v0 = *(const float4*)(emb + k * D_DIM + g * 8);
    const float4 v1 = *(const float4*)(emb + k * D_DIM + g * 8 + 4);
    ushort_t o[8];
    o[0] = f2bf(v0.x); o[1] = f2bf(v0.y); o[2] = f2bf(v0.z); o[3] = f2bf(v0.w);
    o[4] = f2bf(v1.x); o[5] = f2bf(v1.y); o[6] = f2bf(v1.z); o[7] = f2bf(v1.w);
    *(bf16x8*)(Bg + ((size_t)g * K_CODES + k) * 8) = *(bf16x8*)o;
    float s = v0.x * v0.x + v0.y * v0.y + v0.z * v0.z + v0.w * v0.w
            + v1.x * v1.x + v1.y * v1.y + v1.z * v1.z + v1.w * v1.w;
#pragma unroll
    for (int off = 16; off >= 1; off >>= 1) s += __shfl_xor(s, off);   // all 32 lanes
    if (g < 2) {   // planes 32,33: replicated bf16(-enorm/32)
        const ushort_t ev = f2bf(s * -0.03125f);
        ushort_t eo[8];
#pragma unroll
        for (int j = 0; j < 8; ++j) eo[j] = ev;
        *(bf16x8*)(Bg + ((size_t)(32 + g) * K_CODES + k) * 8) = *(bf16x8*)eo;
    }
    if (gi < 32) ctrl->lsum[gi] = 0ull;
    if (gi == 32) ctrl->done = 0u;
}

// ---------------- K2: main ----------------
__global__ __launch_bounds__(512, 2) void vq_main(
        const float* __restrict__ z, const float* __restrict__ emb,
        const ushort_t* __restrict__ Bg,
        float* __restrict__ out, float* __restrict__ loss, Ctrl* __restrict__ ctrl) {
    // LDS layout (bytes):
    //   As   [     0, 32768)  [32 planes][64 rows][8] bf16 (RO after prologue)
    //   et   [ 32768, 99328)  [64][260] f32 (epilogue gather)
    //   znp  [ 99328,101376)  [64][8] f32 (prologue partials)
    //   znL  [101376,101632)  [64] f32
    //   pmin [101632,105728)  [64][8] u64   <-- 4096 B (R12 bug: overflowed smem)
    //   idxL [105728,105984)  [64] i32
    __shared__ __align__(16) char smem[105984];
    ushort_t* As  = (ushort_t*)smem;
    float*    et  = (float*)(smem + 32768);
    float*    znp = (float*)(smem + 99328);
    float*    znL = (float*)(smem + 101376);
    u64*      pmin = (u64*)(smem + 101632);
    int*      idxL = (int*)(smem + 105728);

    const int bid = blockIdx.x, tid = threadIdx.x;
    const int b = bid >> 4;
    const int hw0 = (bid & 15) * 64;
    const int w = tid >> 6, l = tid & 63;            // wave w owns codes [w*128, w*128+128)
    const int lane31 = l & 31, hi = l >> 5;

    // ---- B frag load: plane pair (2t, 2t+1); lane31 -> code, hi -> plane parity
    auto loadB = [&](int t, bf16x8* bb) {
        const ushort_t* p = Bg + (((size_t)(t * 2 + hi)) * K_CODES + w * 128 + lane31) * 8;
        bb[0] = *(const bf16x8*)(p);
        bb[1] = *(const bf16x8*)(p + 32 * 8);
        bb[2] = *(const bf16x8*)(p + 64 * 8);
        bb[3] = *(const bf16x8*)(p + 96 * 8);
    };

    f32x16 acc0[4], acc1[4];                         // [code-tile] x rows {lane31, 32+lane31}
    bf16x8 bA[4], bB[4];
    loadB(0, bA);                                    // chunks 0,1 fly under the prologue
    loadB(1, bB);

    // ---- prologue: z -> As bf16 (coalesced 256B-segment loads) + znorm ----
    {
        const float* zb = z + (size_t)b * (D_DIM * 1024) + hw0;
        const int hw = tid & 63, gs = tid >> 6;      // gs in [0,8)
        float zn = 0.f;
#pragma unroll
        for (int gi = 0; gi < 4; ++gi) {
            const int g = gs * 4 + gi;               // granule plane [0,32)
            float v[8]; ushort_t o[8];
#pragma unroll
            for (int j = 0; j < 8; ++j) v[j] = zb[(size_t)(g * 8 + j) * 1024 + hw];
#pragma unroll
            for (int j = 0; j < 8; ++j) { zn += v[j] * v[j]; o[j] = f2bf(v[j]); }
            *(bf16x8*)(As + ((size_t)g * 64 + hw) * 8) = *(bf16x8*)o;
        }
        znp[hw * 8 + gs] = zn;
        __syncthreads();                             // As + znp ready
        if (tid < 64) {
            float s = 0.f;
#pragma unroll
            for (int g = 0; g < 8; ++g) s += znp[tid * 8 + g];
            znL[tid] = s;                            // written & later read by wave 0 only
        }
    }

#pragma unroll
    for (int cf = 0; cf < 4; ++cf)
#pragma unroll
        for (int r = 0; r < 16; ++r) { acc0[cf][r] = 0.f; acc1[cf][r] = 0.f; }

    // ---- K loop: 17 chunks, BARRIER-FREE, reg ping-pong 2-ahead ----
    auto computeC = [&](int t, const bf16x8* bb) {
        const bf16x8 a0 = *(const bf16x8*)(As + ((size_t)(t * 2 + hi) * 64 + lane31) * 8);
        const bf16x8 a1 = *(const bf16x8*)(As + ((size_t)(t * 2 + hi) * 64 + 32 + lane31) * 8);
        __builtin_amdgcn_s_setprio(1);
#pragma unroll
        for (int cf = 0; cf < 4; ++cf) {
            acc0[cf] = __builtin_amdgcn_mfma_f32_32x32x16_bf16(bb[cf], a0, acc0[cf], 0, 0, 0);
            acc1[cf] = __builtin_amdgcn_mfma_f32_32x32x16_bf16(bb[cf], a1, acc1[cf], 0, 0, 0);
        }
        __builtin_amdgcn_s_setprio(0);
    };

#pragma unroll
    for (int tt = 0; tt < 8; ++tt) {                 // chunks 2tt, 2tt+1
        computeC(2 * tt, bA);
        loadB(2 * tt + 2, bA);                       // 2tt+2 <= 16 always
        computeC(2 * tt + 1, bB);
        if (tt < 7) loadB(2 * tt + 3, bB);
    }
    {   // chunk 16 = enorm planes (32,33): A = all-ones (k=16 x -enorm/32 = -enorm/2)
        bf16x8 aone;
#pragma unroll
        for (int j = 0; j < 8; ++j) aone[j] = (short)0x3F80;   // bf16 1.0
        __builtin_amdgcn_s_setprio(1);
#pragma unroll
        for (int cf = 0; cf < 4; ++cf) {
            acc0[cf] = __builtin_amdgcn_mfma_f32_32x32x16_bf16(bA[cf], aone, acc0[cf], 0, 0, 0);
            acc1[cf] = __builtin_amdgcn_mfma_f32_32x32x16_bf16(bA[cf], aone, acc1[cf], 0, 0, 0);
        }
        __builtin_amdgcn_s_setprio(0);
    }

    // ---- epilogue: lane-local argmax (acc = z.e - enorm/2); no acc pointers ----
#define REDUCE_ROW(ACC, MI) do {                                                \
        float m = ACC[0][0];                                                    \
        _Pragma("unroll")                                                       \
        for (int cf = 0; cf < 4; ++cf)                                          \
            _Pragma("unroll")                                                   \
            for (int r = 0; r < 16; ++r) m = fmaxf(m, ACC[cf][r]);              \
        unsigned cc = 0xffffffffu;                                              \
        _Pragma("unroll")                                                       \
        for (int cf = 0; cf < 4; ++cf)                                          \
            _Pragma("unroll")                                                   \
            for (int r = 0; r < 16; ++r) {                                      \
                const unsigned cst = (unsigned)(cf * 32 + (r & 3) + 8 * (r >> 2)); \
                if (ACC[cf][r] == m) cc = cst < cc ? cst : cc;                  \
            }                                                                   \
        unsigned code = cc + (unsigned)(w * 128 + 4 * hi);                      \
        const float om = __shfl_xor(m, 32);                                     \
        const unsigned oc = __shfl_xor(code, 32);                               \
        if (om > m || (om == m && oc < code)) { m = om; code = oc; }            \
        unsigned sb = __float_as_uint(m);                                       \
        unsigned s = sb ^ (unsigned)(((int)sb >> 31) | 0x80000000);             \
        u64 key = ((u64)(~s) << 32) | code;                                     \
        if (l < 32) pmin[((MI) * 32 + lane31) * 8 + w] = key;                   \
    } while (0)

    REDUCE_ROW(acc0, 0);
    REDUCE_ROW(acc1, 1);
#undef REDUCE_ROW
    __syncthreads();

    // ---- final per-row min across 8 waves -> idx + striped loss ----
    if (tid < 64) {
        u64 best = pmin[tid * 8];
#pragma unroll
        for (int i = 1; i < 8; ++i) { u64 qv = pmin[tid * 8 + i]; if (qv < best) best = qv; }
        idxL[tid] = (int)(best & 1023u);
        unsigned us = ~(unsigned)(best >> 32);
        unsigned fb = (us & 0x80000000u) ? (us ^ 0x80000000u) : ~us;
        float sc = __uint_as_float(fb);              // max(z.e - enorm/2)
        float lp = znL[tid] - 2.0f * sc;             // ||z||^2 + enorm - 2 z.e
#pragma unroll
        for (int off = 32; off >= 1; off >>= 1) lp += __shfl_xor(lp, off);
        if (tid == 0) {
            u64 fix = (u64)(long long)((double)lp * 1048576.0);
            atomicAdd(&ctrl->lsum[bid & 31], fix);   // <=8 blocks per cell
            __threadfence();
            unsigned old = atomicAdd(&ctrl->done, 1u);
            if (old == (NBLK - 1)) {
                __threadfence();
                u64 tot = 0ull;
#pragma unroll
                for (int i = 0; i < 32; ++i) tot += atomicAdd(&ctrl->lsum[i], 0ull);
                loss[0] = (float)((double)tot * (1.25 / (1048576.0 * 4194304.0)));
            }
        }
    }
    __syncthreads();   // idxL ready

    // ---- gather emb rows -> et[local row] (1 KB coalesced per wave pass) ----
#pragma unroll
    for (int jj = 0; jj < 8; ++jj) {
        int j = jj * 512 + tid;                      // row = j>>6 in [0,64), gr = j&63
        int mrow = j >> 6, gr = j & 63;
        float4 v = *(const float4*)(emb + (size_t)idxL[mrow] * D_DIM + gr * 4);
        *(float4*)(et + mrow * 260 + gr * 4) = v;
    }
    __syncthreads();

    // ---- out[b][d][hw0+hw] = et[hw][d] ----
    const int hw4 = (tid & 15) * 4;
    const int dr = tid >> 4;                         // 0..31
#pragma unroll
    for (int it = 0; it < 8; ++it) {
        const int d = it * 32 + dr;
        float4 qv;
        qv.x = et[(hw4 + 0) * 260 + d];
        qv.y = et[(hw4 + 1) * 260 + d];
        qv.z = et[(hw4 + 2) * 260 + d];
        qv.w = et[(hw4 + 3) * 260 + d];
        *(float4*)(out + ((size_t)(b * 256 + d)) * 1024 + hw0 + hw4) = qv;
    }
}

extern "C" void kernel_launch(void* const* d_in, const int* in_sizes, int n_in,
                              void* d_out, int out_size, void* d_ws, size_t ws_size,
                              hipStream_t stream) {
    const float* z   = (const float*)d_in[0];
    const float* emb = (const float*)d_in[1];
    float* out  = (float*)d_out;
    float* loss = out + ZQ_SIZE;

    char* ws = (char*)d_ws;
    ushort_t* Bg = (ushort_t*)(ws);           //  557,056 B  [34][1024] 16B granules
    Ctrl* ctrl   = (Ctrl*)(ws + 557056);      //      288 B

    vq_prep<<<64, 512, 0, stream>>>(emb, Bg, ctrl);
    vq_main<<<NBLK, 512, 0, stream>>>(z, emb, Bg, out, loss, ctrl);
}